// Round 2
// baseline (2032.245 us; speedup 1.0000x reference)
//
#include <hip/hip_runtime.h>
#include <hip/hip_bf16.h>
#include <math.h>

#define HW 65536
#define NPIX 131072   // B*HW
#define WIMG 256

typedef unsigned short u16;

__device__ __forceinline__ float b2f(u16 u) {
  union { unsigned int i; float f; } c; c.i = ((unsigned int)u) << 16; return c.f;
}
__device__ __forceinline__ u16 f2b(float f) {
  union { float f; unsigned int i; } c; c.f = f;
  unsigned int i = c.i;
  return (u16)((i + 0x7fffu + ((i >> 16) & 1u)) >> 16);  // RNE
}
__device__ __forceinline__ void unpack2(unsigned int u, float& a, float& b) {
  union { unsigned int i; float f; } x, y;
  x.i = u << 16; y.i = u & 0xffff0000u; a = x.f; b = y.f;
}
__device__ __forceinline__ float gelu_exact(float x) {
  return 0.5f * x * (1.0f + erff(x * 0.70710678118654752f));
}

// ---- LayerNorm over 96 ch per pixel; f32 [B][96][HW] in -> bf16 [96][NPIX] out
__global__ __launch_bounds__(256) void ln_kernel(const float* __restrict__ in,
                                                 u16* __restrict__ out) {
  int p = blockIdx.x * 256 + threadIdx.x;
  int b = p >> 16, hw = p & (HW - 1);
  const float* src = in + (size_t)b * 96 * HW + hw;
  float s = 0.f, s2 = 0.f;
  #pragma unroll 8
  for (int c = 0; c < 96; c++) { float v = src[(size_t)c * HW]; s += v; s2 += v * v; }
  float mu = s * (1.f / 96.f);
  float rstd = rsqrtf(s2 * (1.f / 96.f) - mu * mu + 1e-5f);
  u16* dst = out + p;
  #pragma unroll 8
  for (int c = 0; c < 96; c++) dst[(size_t)c * NPIX] = f2b((src[(size_t)c * HW] - mu) * rstd);
}

// ---- 1x1 conv GEMM: in bf16 [CIN][NPIX], w f32 [COUT][wstride]
// OUTMODE 0: out bf16 [COUT][NPIX].  OUTMODE 1: out f32 [B][COUT][HW] += resid
template<int CIN, int COUT, int ACT, int OUTMODE>
__global__ __launch_bounds__(256) void pw_kernel(const u16* __restrict__ in,
                                                 const float* __restrict__ w, int wstride,
                                                 const float* __restrict__ resid,
                                                 void* __restrict__ outv) {
  int pix0 = blockIdx.x * 128;
  int o0 = blockIdx.y * 64;
  __shared__ float sIn[16][128];
  __shared__ float sW[64][17];
  int t = threadIdx.x;
  int tx = t & 15, ty = t >> 4;
  float acc[4][8];
  #pragma unroll
  for (int i = 0; i < 4; i++)
    #pragma unroll
    for (int j = 0; j < 8; j++) acc[i][j] = 0.f;

  int kk_s = t >> 4, px8 = (t & 15) * 8;
  for (int k0 = 0; k0 < CIN; k0 += 16) {
    uint4 raw = *(const uint4*)(in + (size_t)(k0 + kk_s) * NPIX + pix0 + px8);
    float f[8];
    unpack2(raw.x, f[0], f[1]); unpack2(raw.y, f[2], f[3]);
    unpack2(raw.z, f[4], f[5]); unpack2(raw.w, f[6], f[7]);
    #pragma unroll
    for (int j = 0; j < 8; j++) sIn[kk_s][px8 + j] = f[j];
    #pragma unroll
    for (int j = 0; j < 4; j++) {
      int idx = t + j * 256; int oo = idx >> 4, kk = idx & 15;
      float wv = 0.f;
      if (o0 + oo < COUT) wv = w[(size_t)(o0 + oo) * wstride + k0 + kk];
      sW[oo][kk] = wv;
    }
    __syncthreads();
    #pragma unroll
    for (int kk = 0; kk < 16; kk++) {
      float a0 = sW[ty * 4 + 0][kk];
      float a1 = sW[ty * 4 + 1][kk];
      float a2 = sW[ty * 4 + 2][kk];
      float a3 = sW[ty * 4 + 3][kk];
      float bv[8];
      #pragma unroll
      for (int j = 0; j < 8; j++) bv[j] = sIn[kk][tx * 8 + j];
      #pragma unroll
      for (int j = 0; j < 8; j++) {
        acc[0][j] += a0 * bv[j];
        acc[1][j] += a1 * bv[j];
        acc[2][j] += a2 * bv[j];
        acc[3][j] += a3 * bv[j];
      }
    }
    __syncthreads();
  }
  if (OUTMODE == 0) {
    u16* out = (u16*)outv;
    #pragma unroll
    for (int i = 0; i < 4; i++) {
      int o = o0 + ty * 4 + i;
      if (o < COUT) {
        #pragma unroll
        for (int j = 0; j < 8; j++) {
          float v = acc[i][j];
          if (ACT == 1) v = gelu_exact(v);
          out[(size_t)o * NPIX + pix0 + tx * 8 + j] = f2b(v);
        }
      }
    }
  } else {
    float* out = (float*)outv;
    int p0 = pix0 + tx * 8;
    int b = p0 >> 16, hw0 = p0 & (HW - 1);
    #pragma unroll
    for (int i = 0; i < 4; i++) {
      int o = o0 + ty * 4 + i;
      if (o < COUT) {
        size_t base = (size_t)b * COUT * HW + (size_t)o * HW + hw0;
        #pragma unroll
        for (int j = 0; j < 8; j++) {
          float v = acc[i][j];
          if (ACT == 1) v = gelu_exact(v);
          out[base + j] = v + resid[base + j];
        }
      }
    }
  }
}

// ---- 3x3 depthwise/grouped conv, pad 1
// out ch c: input ch cin = (chdiv==1? c : c/chdiv); if cin<split read bf16 plane
// inA[(cin+offA)*NPIX + b*HW], else f32 inB[b][cin-split][HW]. out bf16 plane c.
__global__ __launch_bounds__(256) void dw3x3_kernel(const u16* __restrict__ inA, int offA,
    const float* __restrict__ inB, int split, int chdiv,
    const float* __restrict__ w9, u16* __restrict__ out, int act) {
  int b = blockIdx.z, c = blockIdx.y;
  int hw = blockIdx.x * 256 + threadIdx.x;
  int h = hw >> 8, wx = hw & 255;
  int cin = (chdiv == 1) ? c : (c / chdiv);
  const float* wp = w9 + c * 9;
  bool useA = cin < split;
  const u16* pa = inA + (size_t)(cin + offA) * NPIX + (size_t)b * HW;
  const float* pb = useA ? nullptr : (inB + (size_t)b * 96 * HW + (size_t)(cin - split) * HW);
  float acc = 0.f;
  #pragma unroll
  for (int dy = -1; dy <= 1; dy++) {
    int hh = h + dy;
    if (hh < 0 || hh >= WIMG) continue;
    #pragma unroll
    for (int dx = -1; dx <= 1; dx++) {
      int ww = wx + dx;
      if (ww < 0 || ww >= WIMG) continue;
      float v = useA ? b2f(pa[hh * WIMG + ww]) : pb[hh * WIMG + ww];
      acc += wp[(dy + 1) * 3 + (dx + 1)] * v;
    }
  }
  if (act) acc = gelu_exact(acc);
  out[(size_t)c * NPIX + (size_t)b * HW + hw] = f2b(acc);
}

// ---- L2 norms of q planes (ids 0..191) and k planes (192..383) over HW
__global__ __launch_bounds__(256) void l2norm_kernel(const u16* __restrict__ q,
                                                     const u16* __restrict__ k,
                                                     float* __restrict__ inv) {
  int id = blockIdx.x;
  const u16* plane;
  if (id < 192) plane = q + (size_t)(id % 96) * NPIX + (size_t)(id / 96) * HW;
  else { int j = id - 192; plane = k + (size_t)(j % 96) * NPIX + (size_t)(j / 96) * HW; }
  float s = 0.f;
  for (int i = threadIdx.x * 8; i < HW; i += 2048) {
    uint4 r = *(const uint4*)(plane + i);
    float f[8];
    unpack2(r.x, f[0], f[1]); unpack2(r.y, f[2], f[3]);
    unpack2(r.z, f[4], f[5]); unpack2(r.w, f[6], f[7]);
    #pragma unroll
    for (int j = 0; j < 8; j++) s += f[j] * f[j];
  }
  #pragma unroll
  for (int off = 32; off >= 1; off >>= 1) s += __shfl_down(s, off);
  __shared__ float red[4];
  if ((threadIdx.x & 63) == 0) red[threadIdx.x >> 6] = s;
  __syncthreads();
  if (threadIdx.x == 0)
    inv[id] = 1.f / fmaxf(sqrtf(red[0] + red[1] + red[2] + red[3]), 1e-12f);
}

// ---- attention partials: 16x16 per (b,h), 64 L-chunks of 1024
__global__ __launch_bounds__(256) void attn_partial_kernel(const u16* __restrict__ q,
                                                           const u16* __restrict__ k,
                                                           float* __restrict__ part) {
  int bh = blockIdx.x, chunk = blockIdx.y;
  int b = bh / 6, h = bh % 6;
  int t = threadIdx.x, c = t >> 4, d = t & 15;
  const u16* qp = q + (size_t)(h * 16 + c) * NPIX + (size_t)b * HW + chunk * 1024;
  const u16* kp = k + (size_t)(h * 16 + d) * NPIX + (size_t)b * HW + chunk * 1024;
  float acc = 0.f;
  for (int l = 0; l < 1024; l += 8) {
    uint4 rq = *(const uint4*)(qp + l);
    uint4 rk = *(const uint4*)(kp + l);
    float qa[8], ka[8];
    unpack2(rq.x, qa[0], qa[1]); unpack2(rq.y, qa[2], qa[3]);
    unpack2(rq.z, qa[4], qa[5]); unpack2(rq.w, qa[6], qa[7]);
    unpack2(rk.x, ka[0], ka[1]); unpack2(rk.y, ka[2], ka[3]);
    unpack2(rk.z, ka[4], ka[5]); unpack2(rk.w, ka[6], ka[7]);
    #pragma unroll
    for (int j = 0; j < 8; j++) acc += qa[j] * ka[j];
  }
  part[chunk * 3072 + bh * 256 + t] = acc;
}

// ---- combine partials, scale by norms & temperature, softmax over d
__global__ __launch_bounds__(256) void attn_softmax_kernel(const float* __restrict__ part,
                                                           const float* __restrict__ inv,
                                                           const float* __restrict__ temp,
                                                           float* __restrict__ attn) {
  int bh = blockIdx.x;
  int b = bh / 6, h = bh % 6;
  int t = threadIdx.x;
  int c = t >> 4, d = t & 15;
  float s = 0.f;
  for (int ch = 0; ch < 64; ch++) s += part[ch * 3072 + bh * 256 + t];
  float val = s * inv[b * 96 + h * 16 + c] * inv[192 + b * 96 + h * 16 + d] * temp[h];
  float m = val;
  #pragma unroll
  for (int off = 1; off < 16; off <<= 1) m = fmaxf(m, __shfl_xor(m, off));
  float e = expf(val - m);
  float sum = e;
  #pragma unroll
  for (int off = 1; off < 16; off <<= 1) sum += __shfl_xor(sum, off);
  attn[bh * 256 + t] = e / sum;
}

// ---- out[h*16+c] = sum_d attn[b,h,c,d] * v[h*16+d] per pixel
__global__ __launch_bounds__(256) void attnout_kernel(const float* __restrict__ attn,
                                                      const u16* __restrict__ v,
                                                      u16* __restrict__ out) {
  __shared__ float sA[1536];
  int t = threadIdx.x;
  int p = blockIdx.x * 256 + t;
  int b = p >> 16;
  for (int i = t; i < 1536; i += 256) sA[i] = attn[b * 1536 + i];
  __syncthreads();
  const u16* vb = v + p;
  u16* ob = out + p;
  for (int h = 0; h < 6; h++) {
    float vv[16];
    #pragma unroll
    for (int d = 0; d < 16; d++) vv[d] = b2f(vb[(size_t)(h * 16 + d) * NPIX]);
    #pragma unroll
    for (int c = 0; c < 16; c++) {
      float s = 0.f;
      #pragma unroll
      for (int d = 0; d < 16; d++) s += sA[h * 256 + c * 16 + d] * vv[d];
      ob[(size_t)(h * 16 + c) * NPIX] = f2b(s);
    }
  }
}

extern "C" void kernel_launch(void* const* d_in, const int* in_sizes, int n_in,
                              void* d_out, int out_size, void* d_ws, size_t ws_size,
                              hipStream_t stream) {
  const float* x       = (const float*)d_in[0];
  const float* f1      = (const float*)d_in[1];
  const float* f2      = (const float*)d_in[2];
  const float* qkv_w   = (const float*)d_in[3];
  const float* qkv_dw  = (const float*)d_in[4];
  const float* temp    = (const float*)d_in[5];
  const float* k_dw    = (const float*)d_in[6];
  const float* k_pw    = (const float*)d_in[7];
  const float* v_dw    = (const float*)d_in[8];
  const float* v_pw    = (const float*)d_in[9];
  const float* proj_w  = (const float*)d_in[10];
  const float* ffn_dw1 = (const float*)d_in[11];
  const float* ffn_pm  = (const float*)d_in[12];
  const float* ffn_dw2 = (const float*)d_in[13];
  const float* ffn_po  = (const float*)d_in[14];
  float* out = (float*)d_out;

  // workspace: 7 bf16 slots of 96 planes each + small f32 scratch  (~177 MB)
  u16* wsb = (u16*)d_ws;
  const size_t SLOT = (size_t)96 * NPIX;
  u16* S0 = wsb;
  u16* S1 = wsb + 1 * SLOT;
  u16* S2 = wsb + 2 * SLOT;
  u16* S3 = wsb + 3 * SLOT;
  u16* S4 = wsb + 4 * SLOT;
  float* fscr = (float*)(wsb + 7 * SLOT);
  float* INV  = fscr;                 // 384
  float* PART = fscr + 384;           // 64*3072
  float* ATTN = fscr + 384 + 196608;  // 3072

  dim3 blk(256);

  // ---- attention branch ----
  ln_kernel<<<512, blk, 0, stream>>>(x, S0);
  pw_kernel<96, 288, 0, 0><<<dim3(1024, 5), blk, 0, stream>>>(S0, qkv_w, 96, nullptr, S1);
  // qkv depthwise, 96-ch groups with slot rotation: q->S0, k->S1, v->S2
  dw3x3_kernel<<<dim3(256, 96, 2), blk, 0, stream>>>(S1, 0,   x, 288, 1, qkv_dw,          S0, 0);
  dw3x3_kernel<<<dim3(256, 96, 2), blk, 0, stream>>>(S1, 96,  x, 288, 1, qkv_dw + 96 * 9, S1, 0);
  dw3x3_kernel<<<dim3(256, 96, 2), blk, 0, stream>>>(S1, 192, x, 288, 1, qkv_dw + 192 * 9, S2, 0);
  // k path: concat(k=S1, f1) -> dw+gelu -> S3,S4 ; pw -> S1
  dw3x3_kernel<<<dim3(256, 192, 2), blk, 0, stream>>>(S1, 0, f1, 96, 1, k_dw, S3, 1);
  pw_kernel<192, 96, 0, 0><<<dim3(1024, 2), blk, 0, stream>>>(S3, k_pw, 192, nullptr, S1);
  // v path: concat(v=S2, f2) -> dw+gelu -> S3,S4 ; pw -> S2
  dw3x3_kernel<<<dim3(256, 192, 2), blk, 0, stream>>>(S2, 0, f2, 96, 1, v_dw, S3, 1);
  pw_kernel<192, 96, 0, 0><<<dim3(1024, 2), blk, 0, stream>>>(S3, v_pw, 192, nullptr, S2);
  // norms + attention matrix + softmax + apply
  l2norm_kernel<<<384, blk, 0, stream>>>(S0, S1, INV);
  attn_partial_kernel<<<dim3(12, 64), blk, 0, stream>>>(S0, S1, PART);
  attn_softmax_kernel<<<12, blk, 0, stream>>>(PART, INV, temp, ATTN);
  attnout_kernel<<<512, blk, 0, stream>>>(ATTN, S2, S3);
  // proj + residual -> d_out (f32, b-major)
  pw_kernel<96, 96, 0, 1><<<dim3(1024, 2), blk, 0, stream>>>(S3, proj_w, 96, x, out);

  // ---- FFN branch ----
  ln_kernel<<<512, blk, 0, stream>>>(out, S0);
  // grouped dw 96->288 (out ch o reads in ch o/3) -> S1..S3
  dw3x3_kernel<<<dim3(256, 288, 2), blk, 0, stream>>>(S0, 0, x, 96, 3, ffn_dw1, S1, 0);
  // 288x288 pw + gelu -> S4..S6
  pw_kernel<288, 288, 1, 0><<<dim3(1024, 5), blk, 0, stream>>>(S1, ffn_pm, 288, nullptr, S4);
  // depthwise 3x3 -> S1..S3
  dw3x3_kernel<<<dim3(256, 288, 2), blk, 0, stream>>>(S4, 0, x, 288, 1, ffn_dw2, S1, 0);
  // 288->96 pw + residual -> d_out
  pw_kernel<288, 96, 0, 1><<<dim3(1024, 2), blk, 0, stream>>>(S1, ffn_po, 288, out, out);
}

// Round 3
// 1451.045 us; speedup vs baseline: 1.4005x; 1.4005x over previous
//
#include <hip/hip_runtime.h>
#include <hip/hip_bf16.h>
#include <math.h>

#define HW 65536
#define NPIX 131072   // B*HW
#define WIMG 256

typedef unsigned short u16;
typedef __attribute__((ext_vector_type(8))) short bf16x8;
typedef __attribute__((ext_vector_type(4))) float f32x4;

__device__ __forceinline__ float b2f(u16 u) {
  union { unsigned int i; float f; } c; c.i = ((unsigned int)u) << 16; return c.f;
}
__device__ __forceinline__ u16 f2b(float f) {
  union { float f; unsigned int i; } c; c.f = f;
  unsigned int i = c.i;
  return (u16)((i + 0x7fffu + ((i >> 16) & 1u)) >> 16);  // RNE
}
__device__ __forceinline__ void unpack2(unsigned int u, float& a, float& b) {
  union { unsigned int i; float f; } x, y;
  x.i = u << 16; y.i = u & 0xffff0000u; a = x.f; b = y.f;
}
__device__ __forceinline__ float gelu_exact(float x) {
  return 0.5f * x * (1.0f + erff(x * 0.70710678118654752f));
}

// ---- pack f32 weights -> bf16, all matrices concatenated ----
__global__ __launch_bounds__(256) void wpack_kernel(
    const float* s0, int n0, const float* s1, int n1, const float* s2, int n2,
    const float* s3, int n3, const float* s4, int n4, const float* s5, int n5,
    u16* out) {
  int i = blockIdx.x * 256 + threadIdx.x;
  const float* s; int local = i;
  if (local < n0) { s = s0; }
  else { local -= n0; if (local < n1) s = s1;
  else { local -= n1; if (local < n2) s = s2;
  else { local -= n2; if (local < n3) s = s3;
  else { local -= n3; if (local < n4) s = s4;
  else { local -= n4; if (local >= n5) return; s = s5; } } } } }
  out[i] = f2b(s[local]);
}

// ---- LayerNorm over 96 ch per pixel; f32 [B][96][HW] in -> bf16 [96][NPIX] out
__global__ __launch_bounds__(256) void ln_kernel(const float* __restrict__ in,
                                                 u16* __restrict__ out) {
  int p = blockIdx.x * 256 + threadIdx.x;
  int b = p >> 16, hw = p & (HW - 1);
  const float* src = in + (size_t)b * 96 * HW + hw;
  float s = 0.f, s2 = 0.f;
  #pragma unroll 8
  for (int c = 0; c < 96; c++) { float v = src[(size_t)c * HW]; s += v; s2 += v * v; }
  float mu = s * (1.f / 96.f);
  float rstd = rsqrtf(s2 * (1.f / 96.f) - mu * mu + 1e-5f);
  u16* dst = out + p;
  #pragma unroll 8
  for (int c = 0; c < 96; c++) dst[(size_t)c * NPIX] = f2b((src[(size_t)c * HW] - mu) * rstd);
}

// ---- 1x1 conv as bf16 MFMA GEMM: Out[COUT][NPIX] = W[COUT][CIN] * In[CIN][NPIX]
// grid (COUT/96, NPIX/128), block 256 = 4 waves (2M x 2N), BM=96 BN=128 BK=32
// OUTMODE 0: out bf16 [COUT][NPIX].  OUTMODE 1: out f32 [B][COUT][HW] = acc + resid
template<int CIN, int COUT, int ACT, int OUTMODE>
__global__ __launch_bounds__(256) void pwm_kernel(const u16* __restrict__ in,
                                                  const u16* __restrict__ wb,
                                                  const float* __restrict__ resid,
                                                  void* __restrict__ outv) {
  int mblk = blockIdx.x;
  int pix0 = blockIdx.y * 128;
  __shared__ u16 sB[128 * 32];  // element (px,k) at px*32 + ((k>>2)^((px>>3)&7))*4 + (k&3)
  int t = threadIdx.x;
  int lane = t & 63, w = t >> 6;
  int wm = w & 1, wn = w >> 1;
  int l15 = lane & 15, g = lane >> 4;

  f32x4 acc[3][4];
  #pragma unroll
  for (int i = 0; i < 3; i++)
    #pragma unroll
    for (int j = 0; j < 4; j++) acc[i][j] = (f32x4){0.f, 0.f, 0.f, 0.f};

  // staging: thread t loads k rows (t>>4) and (t>>4)+16, px (t&15)*8 .. +7
  int spx = (t & 15) * 8;
  int sk = t >> 4;
  const u16* gsrc = in + (size_t)sk * NPIX + pix0 + spx;
  int swz_s = (t & 15) & 7;
  u16* swr0 = sB + spx * 32 + (((sk >> 2) ^ swz_s) << 2) + (sk & 3);
  u16* swr1 = sB + spx * 32 + ((((sk >> 2) + 4) ^ swz_s) << 2) + (sk & 3);

  // A: lane row = mblk*96 + wm*48 + fm*16 + l15
  const u16* wbase = wb + (size_t)(mblk * 96 + wm * 48 + l15) * CIN;

  for (int k0 = 0; k0 < CIN; k0 += 32) {
    union { uint4 v; u16 s[8]; } r0, r1;
    r0.v = *(const uint4*)(gsrc + (size_t)k0 * NPIX);
    r1.v = *(const uint4*)(gsrc + (size_t)(k0 + 16) * NPIX);
    #pragma unroll
    for (int j = 0; j < 8; j++) swr0[j * 32] = r0.s[j];
    #pragma unroll
    for (int j = 0; j < 8; j++) swr1[j * 32] = r1.s[j];
    __syncthreads();

    // A fragments: slots 0-3 <- k0+4g+{0..3}, slots 4-7 <- k0+16+4g+{0..3}
    bf16x8 afr[3];
    #pragma unroll
    for (int fm = 0; fm < 3; fm++) {
      const u16* wp = wbase + (size_t)fm * 16 * CIN + k0;
      ushort4 a0 = *(const ushort4*)(wp + 4 * g);
      ushort4 a1 = *(const ushort4*)(wp + 16 + 4 * g);
      bf16x8 a;
      a[0] = (short)a0.x; a[1] = (short)a0.y; a[2] = (short)a0.z; a[3] = (short)a0.w;
      a[4] = (short)a1.x; a[5] = (short)a1.y; a[6] = (short)a1.z; a[7] = (short)a1.w;
      afr[fm] = a;
    }
    // B fragments + MFMA
    #pragma unroll
    for (int fn = 0; fn < 4; fn++) {
      int px = wn * 64 + fn * 16 + l15;
      int swz = (px >> 3) & 7;
      const u16* bp = sB + px * 32;
      ushort4 b0 = *(const ushort4*)(bp + ((g ^ swz) << 2));
      ushort4 b1 = *(const ushort4*)(bp + (((g + 4) ^ swz) << 2));
      bf16x8 bfr;
      bfr[0] = (short)b0.x; bfr[1] = (short)b0.y; bfr[2] = (short)b0.z; bfr[3] = (short)b0.w;
      bfr[4] = (short)b1.x; bfr[5] = (short)b1.y; bfr[6] = (short)b1.z; bfr[7] = (short)b1.w;
      #pragma unroll
      for (int fm = 0; fm < 3; fm++)
        acc[fm][fn] = __builtin_amdgcn_mfma_f32_16x16x32_bf16(afr[fm], bfr, acc[fm][fn], 0, 0, 0);
    }
    __syncthreads();
  }

  // epilogue: D row (o) = base + g*4 + reg, col (px) = l15
  int obase = mblk * 96 + wm * 48;
  #pragma unroll
  for (int fm = 0; fm < 3; fm++) {
    #pragma unroll
    for (int fn = 0; fn < 4; fn++) {
      int px = pix0 + wn * 64 + fn * 16 + l15;
      #pragma unroll
      for (int reg = 0; reg < 4; reg++) {
        int o = obase + fm * 16 + g * 4 + reg;
        float v = acc[fm][fn][reg];
        if (ACT == 1) v = gelu_exact(v);
        if (OUTMODE == 0) {
          ((u16*)outv)[(size_t)o * NPIX + px] = f2b(v);
        } else {
          int b = px >> 16, hw = px & (HW - 1);
          size_t idx = ((size_t)b * COUT + o) * HW + hw;
          ((float*)outv)[idx] = v + resid[idx];
        }
      }
    }
  }
}

// ---- 3x3 depthwise/grouped conv, pad 1 (unchanged) ----
__global__ __launch_bounds__(256) void dw3x3_kernel(const u16* __restrict__ inA, int offA,
    const float* __restrict__ inB, int split, int chdiv,
    const float* __restrict__ w9, u16* __restrict__ out, int act) {
  int b = blockIdx.z, c = blockIdx.y;
  int hw = blockIdx.x * 256 + threadIdx.x;
  int h = hw >> 8, wx = hw & 255;
  int cin = (chdiv == 1) ? c : (c / chdiv);
  const float* wp = w9 + c * 9;
  bool useA = cin < split;
  const u16* pa = inA + (size_t)(cin + offA) * NPIX + (size_t)b * HW;
  const float* pb = useA ? nullptr : (inB + (size_t)b * 96 * HW + (size_t)(cin - split) * HW);
  float acc = 0.f;
  #pragma unroll
  for (int dy = -1; dy <= 1; dy++) {
    int hh = h + dy;
    if (hh < 0 || hh >= WIMG) continue;
    #pragma unroll
    for (int dx = -1; dx <= 1; dx++) {
      int ww = wx + dx;
      if (ww < 0 || ww >= WIMG) continue;
      float v = useA ? b2f(pa[hh * WIMG + ww]) : pb[hh * WIMG + ww];
      acc += wp[(dy + 1) * 3 + (dx + 1)] * v;
    }
  }
  if (act) acc = gelu_exact(acc);
  out[(size_t)c * NPIX + (size_t)b * HW + hw] = f2b(acc);
}

// ---- L2 norms of q planes (ids 0..191) and k planes (192..383) over HW
__global__ __launch_bounds__(256) void l2norm_kernel(const u16* __restrict__ q,
                                                     const u16* __restrict__ k,
                                                     float* __restrict__ inv) {
  int id = blockIdx.x;
  const u16* plane;
  if (id < 192) plane = q + (size_t)(id % 96) * NPIX + (size_t)(id / 96) * HW;
  else { int j = id - 192; plane = k + (size_t)(j % 96) * NPIX + (size_t)(j / 96) * HW; }
  float s = 0.f;
  for (int i = threadIdx.x * 8; i < HW; i += 2048) {
    uint4 r = *(const uint4*)(plane + i);
    float f[8];
    unpack2(r.x, f[0], f[1]); unpack2(r.y, f[2], f[3]);
    unpack2(r.z, f[4], f[5]); unpack2(r.w, f[6], f[7]);
    #pragma unroll
    for (int j = 0; j < 8; j++) s += f[j] * f[j];
  }
  #pragma unroll
  for (int off = 32; off >= 1; off >>= 1) s += __shfl_down(s, off);
  __shared__ float red[4];
  if ((threadIdx.x & 63) == 0) red[threadIdx.x >> 6] = s;
  __syncthreads();
  if (threadIdx.x == 0)
    inv[id] = 1.f / fmaxf(sqrtf(red[0] + red[1] + red[2] + red[3]), 1e-12f);
}

// ---- attention partials: 16x16 per (b,h), 64 L-chunks of 1024
__global__ __launch_bounds__(256) void attn_partial_kernel(const u16* __restrict__ q,
                                                           const u16* __restrict__ k,
                                                           float* __restrict__ part) {
  int bh = blockIdx.x, chunk = blockIdx.y;
  int b = bh / 6, h = bh % 6;
  int t = threadIdx.x, c = t >> 4, d = t & 15;
  const u16* qp = q + (size_t)(h * 16 + c) * NPIX + (size_t)b * HW + chunk * 1024;
  const u16* kp = k + (size_t)(h * 16 + d) * NPIX + (size_t)b * HW + chunk * 1024;
  float acc = 0.f;
  for (int l = 0; l < 1024; l += 8) {
    uint4 rq = *(const uint4*)(qp + l);
    uint4 rk = *(const uint4*)(kp + l);
    float qa[8], ka[8];
    unpack2(rq.x, qa[0], qa[1]); unpack2(rq.y, qa[2], qa[3]);
    unpack2(rq.z, qa[4], qa[5]); unpack2(rq.w, qa[6], qa[7]);
    unpack2(rk.x, ka[0], ka[1]); unpack2(rk.y, ka[2], ka[3]);
    unpack2(rk.z, ka[4], ka[5]); unpack2(rk.w, ka[6], ka[7]);
    #pragma unroll
    for (int j = 0; j < 8; j++) acc += qa[j] * ka[j];
  }
  part[chunk * 3072 + bh * 256 + t] = acc;
}

// ---- combine partials, scale by norms & temperature, softmax over d
__global__ __launch_bounds__(256) void attn_softmax_kernel(const float* __restrict__ part,
                                                           const float* __restrict__ inv,
                                                           const float* __restrict__ temp,
                                                           float* __restrict__ attn) {
  int bh = blockIdx.x;
  int b = bh / 6, h = bh % 6;
  int t = threadIdx.x;
  int c = t >> 4, d = t & 15;
  float s = 0.f;
  for (int ch = 0; ch < 64; ch++) s += part[ch * 3072 + bh * 256 + t];
  float val = s * inv[b * 96 + h * 16 + c] * inv[192 + b * 96 + h * 16 + d] * temp[h];
  float m = val;
  #pragma unroll
  for (int off = 1; off < 16; off <<= 1) m = fmaxf(m, __shfl_xor(m, off));
  float e = expf(val - m);
  float sum = e;
  #pragma unroll
  for (int off = 1; off < 16; off <<= 1) sum += __shfl_xor(sum, off);
  attn[bh * 256 + t] = e / sum;
}

// ---- out[h*16+c] = sum_d attn[b,h,c,d] * v[h*16+d] per pixel
__global__ __launch_bounds__(256) void attnout_kernel(const float* __restrict__ attn,
                                                      const u16* __restrict__ v,
                                                      u16* __restrict__ out) {
  __shared__ float sA[1536];
  int t = threadIdx.x;
  int p = blockIdx.x * 256 + t;
  int b = p >> 16;
  for (int i = t; i < 1536; i += 256) sA[i] = attn[b * 1536 + i];
  __syncthreads();
  const u16* vb = v + p;
  u16* ob = out + p;
  for (int h = 0; h < 6; h++) {
    float vv[16];
    #pragma unroll
    for (int d = 0; d < 16; d++) vv[d] = b2f(vb[(size_t)(h * 16 + d) * NPIX]);
    #pragma unroll
    for (int c = 0; c < 16; c++) {
      float s = 0.f;
      #pragma unroll
      for (int d = 0; d < 16; d++) s += sA[h * 256 + c * 16 + d] * vv[d];
      ob[(size_t)(h * 16 + c) * NPIX] = f2b(s);
    }
  }
}

extern "C" void kernel_launch(void* const* d_in, const int* in_sizes, int n_in,
                              void* d_out, int out_size, void* d_ws, size_t ws_size,
                              hipStream_t stream) {
  const float* x       = (const float*)d_in[0];
  const float* f1      = (const float*)d_in[1];
  const float* f2      = (const float*)d_in[2];
  const float* qkv_w   = (const float*)d_in[3];
  const float* qkv_dw  = (const float*)d_in[4];
  const float* temp    = (const float*)d_in[5];
  const float* k_dw    = (const float*)d_in[6];
  const float* k_pw    = (const float*)d_in[7];
  const float* v_dw    = (const float*)d_in[8];
  const float* v_pw    = (const float*)d_in[9];
  const float* proj_w  = (const float*)d_in[10];
  const float* ffn_dw1 = (const float*)d_in[11];
  const float* ffn_pm  = (const float*)d_in[12];
  const float* ffn_dw2 = (const float*)d_in[13];
  const float* ffn_po  = (const float*)d_in[14];
  float* out = (float*)d_out;

  // workspace: 7 bf16 slots (96 planes each) + f32 scratch + packed bf16 weights
  u16* wsb = (u16*)d_ws;
  const size_t SLOT = (size_t)96 * NPIX;
  u16* S0 = wsb;
  u16* S1 = wsb + 1 * SLOT;
  u16* S2 = wsb + 2 * SLOT;
  u16* S3 = wsb + 3 * SLOT;
  u16* S4 = wsb + 4 * SLOT;
  float* fscr = (float*)(wsb + 7 * SLOT);
  float* INV  = fscr;                 // 384
  float* PART = fscr + 384;           // 64*3072
  float* ATTN = fscr + 384 + 196608;  // 3072
  u16* WB = (u16*)(fscr + 200064);
  // packed weight offsets (elements)
  u16* Wqkv = WB;                 // 288*96
  u16* Wkpw = WB + 27648;         // 96*192
  u16* Wvpw = WB + 46080;         // 96*192
  u16* Wproj = WB + 64512;        // 96*96
  u16* Wpm  = WB + 73728;         // 288*288
  u16* Wpo  = WB + 156672;        // 96*288  (total 184320)

  dim3 blk(256);

  wpack_kernel<<<720, blk, 0, stream>>>(qkv_w, 27648, k_pw, 18432, v_pw, 18432,
                                        proj_w, 9216, ffn_pm, 82944, ffn_po, 27648, WB);

  // ---- attention branch ----
  ln_kernel<<<512, blk, 0, stream>>>(x, S0);
  pwm_kernel<96, 288, 0, 0><<<dim3(3, 1024), blk, 0, stream>>>(S0, Wqkv, nullptr, S1);
  // qkv depthwise with slot rotation: q->S0, k->S1, v->S2
  dw3x3_kernel<<<dim3(256, 96, 2), blk, 0, stream>>>(S1, 0,   x, 288, 1, qkv_dw,           S0, 0);
  dw3x3_kernel<<<dim3(256, 96, 2), blk, 0, stream>>>(S1, 96,  x, 288, 1, qkv_dw + 96 * 9,  S1, 0);
  dw3x3_kernel<<<dim3(256, 96, 2), blk, 0, stream>>>(S1, 192, x, 288, 1, qkv_dw + 192 * 9, S2, 0);
  // k path: concat(k=S1, f1) -> dw+gelu -> S3,S4 ; pw -> S1
  dw3x3_kernel<<<dim3(256, 192, 2), blk, 0, stream>>>(S1, 0, f1, 96, 1, k_dw, S3, 1);
  pwm_kernel<192, 96, 0, 0><<<dim3(1, 1024), blk, 0, stream>>>(S3, Wkpw, nullptr, S1);
  // v path: concat(v=S2, f2) -> dw+gelu -> S3,S4 ; pw -> S2
  dw3x3_kernel<<<dim3(256, 192, 2), blk, 0, stream>>>(S2, 0, f2, 96, 1, v_dw, S3, 1);
  pwm_kernel<192, 96, 0, 0><<<dim3(1, 1024), blk, 0, stream>>>(S3, Wvpw, nullptr, S2);
  // norms + attention matrix + softmax + apply
  l2norm_kernel<<<384, blk, 0, stream>>>(S0, S1, INV);
  attn_partial_kernel<<<dim3(12, 64), blk, 0, stream>>>(S0, S1, PART);
  attn_softmax_kernel<<<12, blk, 0, stream>>>(PART, INV, temp, ATTN);
  attnout_kernel<<<512, blk, 0, stream>>>(ATTN, S2, S3);
  // proj + residual -> d_out (f32, b-major)
  pwm_kernel<96, 96, 0, 1><<<dim3(1, 1024), blk, 0, stream>>>(S3, Wproj, x, out);

  // ---- FFN branch ----
  ln_kernel<<<512, blk, 0, stream>>>(out, S0);
  dw3x3_kernel<<<dim3(256, 288, 2), blk, 0, stream>>>(S0, 0, x, 96, 3, ffn_dw1, S1, 0);
  pwm_kernel<288, 288, 1, 0><<<dim3(3, 1024), blk, 0, stream>>>(S1, Wpm, nullptr, S4);
  dw3x3_kernel<<<dim3(256, 288, 2), blk, 0, stream>>>(S4, 0, x, 288, 1, ffn_dw2, S1, 0);
  pwm_kernel<288, 96, 0, 1><<<dim3(1, 1024), blk, 0, stream>>>(S1, Wpo, out, out);
}

// Round 4
// 775.541 us; speedup vs baseline: 2.6204x; 1.8710x over previous
//
#include <hip/hip_runtime.h>
#include <hip/hip_bf16.h>
#include <math.h>

#define HW 65536
#define NPIX 131072   // B*HW
#define WIMG 256

typedef unsigned short u16;
typedef __attribute__((ext_vector_type(8))) short bf16x8;
typedef __attribute__((ext_vector_type(4))) float f32x4;

__device__ __forceinline__ float b2f(u16 u) {
  union { unsigned int i; float f; } c; c.i = ((unsigned int)u) << 16; return c.f;
}
__device__ __forceinline__ u16 f2b(float f) {
  union { float f; unsigned int i; } c; c.f = f;
  unsigned int i = c.i;
  return (u16)((i + 0x7fffu + ((i >> 16) & 1u)) >> 16);  // RNE
}
__device__ __forceinline__ void unpack2(unsigned int u, float& a, float& b) {
  union { unsigned int i; float f; } x, y;
  x.i = u << 16; y.i = u & 0xffff0000u; a = x.f; b = y.f;
}
__device__ __forceinline__ float gelu_exact(float x) {
  return 0.5f * x * (1.0f + erff(x * 0.70710678118654752f));
}

// ---- pack f32 weights -> bf16, all matrices concatenated ----
__global__ __launch_bounds__(256) void wpack_kernel(
    const float* s0, int n0, const float* s1, int n1, const float* s2, int n2,
    const float* s3, int n3, const float* s4, int n4, const float* s5, int n5,
    u16* out) {
  int i = blockIdx.x * 256 + threadIdx.x;
  const float* s; int local = i;
  if (local < n0) { s = s0; }
  else { local -= n0; if (local < n1) s = s1;
  else { local -= n1; if (local < n2) s = s2;
  else { local -= n2; if (local < n3) s = s3;
  else { local -= n3; if (local < n4) s = s4;
  else { local -= n4; if (local >= n5) return; s = s5; } } } } }
  out[i] = f2b(s[local]);
}

// ---- LayerNorm over 96 ch per pixel; f32 [B][96][HW] in -> bf16 [96][NPIX] out
__global__ __launch_bounds__(256) void ln_kernel(const float* __restrict__ in,
                                                 u16* __restrict__ out) {
  int p = blockIdx.x * 256 + threadIdx.x;
  int b = p >> 16, hw = p & (HW - 1);
  const float* src = in + (size_t)b * 96 * HW + hw;
  float s = 0.f, s2 = 0.f;
  #pragma unroll 8
  for (int c = 0; c < 96; c++) { float v = src[(size_t)c * HW]; s += v; s2 += v * v; }
  float mu = s * (1.f / 96.f);
  float rstd = rsqrtf(s2 * (1.f / 96.f) - mu * mu + 1e-5f);
  u16* dst = out + p;
  #pragma unroll 8
  for (int c = 0; c < 96; c++) dst[(size_t)c * NPIX] = f2b((src[(size_t)c * HW] - mu) * rstd);
}

// ---- 1x1 conv as bf16 MFMA GEMM: Out[COUT][NPIX] = W[COUT][CIN] * In[CIN][NPIX]
// grid (COUT/96, NPIX/128), block 256 = 4 waves (2M x 2N), BM=96 BN=128 BK=32
// OUTMODE 0: out bf16 [COUT][NPIX].  OUTMODE 1: out f32 [B][COUT][HW] = acc + resid
template<int CIN, int COUT, int ACT, int OUTMODE>
__global__ __launch_bounds__(256) void pwm_kernel(const u16* __restrict__ in,
                                                  const u16* __restrict__ wb,
                                                  const float* __restrict__ resid,
                                                  void* __restrict__ outv) {
  int mblk = blockIdx.x;
  int pix0 = blockIdx.y * 128;
  __shared__ u16 sB[128 * 32];  // element (px,k) at px*32 + ((k>>2)^((px>>3)&7))*4 + (k&3)
  int t = threadIdx.x;
  int lane = t & 63, w = t >> 6;
  int wm = w & 1, wn = w >> 1;
  int l15 = lane & 15, g = lane >> 4;

  f32x4 acc[3][4];
  #pragma unroll
  for (int i = 0; i < 3; i++)
    #pragma unroll
    for (int j = 0; j < 4; j++) acc[i][j] = (f32x4){0.f, 0.f, 0.f, 0.f};

  int spx = (t & 15) * 8;
  int sk = t >> 4;
  const u16* gsrc = in + (size_t)sk * NPIX + pix0 + spx;
  int swz_s = (t & 15) & 7;
  u16* swr0 = sB + spx * 32 + (((sk >> 2) ^ swz_s) << 2) + (sk & 3);
  u16* swr1 = sB + spx * 32 + ((((sk >> 2) + 4) ^ swz_s) << 2) + (sk & 3);

  const u16* wbase = wb + (size_t)(mblk * 96 + wm * 48 + l15) * CIN;

  for (int k0 = 0; k0 < CIN; k0 += 32) {
    union { uint4 v; u16 s[8]; } r0, r1;
    r0.v = *(const uint4*)(gsrc + (size_t)k0 * NPIX);
    r1.v = *(const uint4*)(gsrc + (size_t)(k0 + 16) * NPIX);
    #pragma unroll
    for (int j = 0; j < 8; j++) swr0[j * 32] = r0.s[j];
    #pragma unroll
    for (int j = 0; j < 8; j++) swr1[j * 32] = r1.s[j];
    __syncthreads();

    bf16x8 afr[3];
    #pragma unroll
    for (int fm = 0; fm < 3; fm++) {
      const u16* wp = wbase + (size_t)fm * 16 * CIN + k0;
      ushort4 a0 = *(const ushort4*)(wp + 4 * g);
      ushort4 a1 = *(const ushort4*)(wp + 16 + 4 * g);
      bf16x8 a;
      a[0] = (short)a0.x; a[1] = (short)a0.y; a[2] = (short)a0.z; a[3] = (short)a0.w;
      a[4] = (short)a1.x; a[5] = (short)a1.y; a[6] = (short)a1.z; a[7] = (short)a1.w;
      afr[fm] = a;
    }
    #pragma unroll
    for (int fn = 0; fn < 4; fn++) {
      int px = wn * 64 + fn * 16 + l15;
      int swz = (px >> 3) & 7;
      const u16* bp = sB + px * 32;
      ushort4 b0 = *(const ushort4*)(bp + ((g ^ swz) << 2));
      ushort4 b1 = *(const ushort4*)(bp + (((g + 4) ^ swz) << 2));
      bf16x8 bfr;
      bfr[0] = (short)b0.x; bfr[1] = (short)b0.y; bfr[2] = (short)b0.z; bfr[3] = (short)b0.w;
      bfr[4] = (short)b1.x; bfr[5] = (short)b1.y; bfr[6] = (short)b1.z; bfr[7] = (short)b1.w;
      #pragma unroll
      for (int fm = 0; fm < 3; fm++)
        acc[fm][fn] = __builtin_amdgcn_mfma_f32_16x16x32_bf16(afr[fm], bfr, acc[fm][fn], 0, 0, 0);
    }
    __syncthreads();
  }

  int obase = mblk * 96 + wm * 48;
  #pragma unroll
  for (int fm = 0; fm < 3; fm++) {
    #pragma unroll
    for (int fn = 0; fn < 4; fn++) {
      int px = pix0 + wn * 64 + fn * 16 + l15;
      #pragma unroll
      for (int reg = 0; reg < 4; reg++) {
        int o = obase + fm * 16 + g * 4 + reg;
        float v = acc[fm][fn][reg];
        if (ACT == 1) v = gelu_exact(v);
        if (OUTMODE == 0) {
          ((u16*)outv)[(size_t)o * NPIX + px] = f2b(v);
        } else {
          int b = px >> 16, hw = px & (HW - 1);
          size_t idx = ((size_t)b * COUT + o) * HW + hw;
          ((float*)outv)[idx] = v + resid[idx];
        }
      }
    }
  }
}

// ---- 3x3 depthwise/grouped conv, pad 1: vectorized, 8 px/thread ----
// out ch c reads cin=(chdiv==1?c:c/chdiv); bf16 inA plane (cin+offA) if cin<split,
// else f32 inB[b][cin-split][HW]. Block: 8 rows x 256 px tile. grid (32, C, B).
template<int ACT>
__global__ __launch_bounds__(256) void dw3x3_kernel(const u16* __restrict__ inA, int offA,
    const float* __restrict__ inB, int split, int chdiv,
    const float* __restrict__ w9, u16* __restrict__ out) {
  int b = blockIdx.z, c = blockIdx.y;
  int t = threadIdx.x;
  int h = blockIdx.x * 8 + (t >> 5);
  int w0 = (t & 31) * 8;
  int cin = (chdiv == 1) ? c : (c / chdiv);
  const float* wp = w9 + c * 9;
  bool useA = cin < split;

  float f[3][10];
  if (useA) {
    const u16* p = inA + (size_t)(cin + offA) * NPIX + (size_t)b * HW;
    #pragma unroll
    for (int dy = 0; dy < 3; dy++) {
      int hh = h + dy - 1;
      if (hh < 0 || hh >= WIMG) {
        #pragma unroll
        for (int j = 0; j < 10; j++) f[dy][j] = 0.f;
        continue;
      }
      const u16* row = p + hh * WIMG;
      union { uint4 v; u16 s[8]; } m;
      m.v = *(const uint4*)(row + w0);
      #pragma unroll
      for (int j = 0; j < 8; j++) f[dy][j + 1] = b2f(m.s[j]);
      f[dy][0] = (w0 > 0) ? b2f(row[w0 - 1]) : 0.f;
      f[dy][9] = (w0 < 248) ? b2f(row[w0 + 8]) : 0.f;
    }
  } else {
    const float* p = inB + (size_t)b * 96 * HW + (size_t)(cin - split) * HW;
    #pragma unroll
    for (int dy = 0; dy < 3; dy++) {
      int hh = h + dy - 1;
      if (hh < 0 || hh >= WIMG) {
        #pragma unroll
        for (int j = 0; j < 10; j++) f[dy][j] = 0.f;
        continue;
      }
      const float* row = p + hh * WIMG;
      float4 m0 = *(const float4*)(row + w0);
      float4 m1 = *(const float4*)(row + w0 + 4);
      f[dy][1] = m0.x; f[dy][2] = m0.y; f[dy][3] = m0.z; f[dy][4] = m0.w;
      f[dy][5] = m1.x; f[dy][6] = m1.y; f[dy][7] = m1.z; f[dy][8] = m1.w;
      f[dy][0] = (w0 > 0) ? row[w0 - 1] : 0.f;
      f[dy][9] = (w0 < 248) ? row[w0 + 8] : 0.f;
    }
  }

  union { uint4 v; u16 s[8]; } r;
  #pragma unroll
  for (int j = 0; j < 8; j++) {
    float acc = 0.f;
    #pragma unroll
    for (int dy = 0; dy < 3; dy++) {
      acc += wp[dy * 3 + 0] * f[dy][j];
      acc += wp[dy * 3 + 1] * f[dy][j + 1];
      acc += wp[dy * 3 + 2] * f[dy][j + 2];
    }
    if (ACT) acc = gelu_exact(acc);
    r.s[j] = f2b(acc);
  }
  *(uint4*)(out + (size_t)c * NPIX + (size_t)b * HW + h * WIMG + w0) = r.v;
}

// ---- L2 norms of q planes (ids 0..191) and k planes (192..383) over HW
__global__ __launch_bounds__(256) void l2norm_kernel(const u16* __restrict__ q,
                                                     const u16* __restrict__ k,
                                                     float* __restrict__ inv) {
  int id = blockIdx.x;
  const u16* plane;
  if (id < 192) plane = q + (size_t)(id % 96) * NPIX + (size_t)(id / 96) * HW;
  else { int j = id - 192; plane = k + (size_t)(j % 96) * NPIX + (size_t)(j / 96) * HW; }
  float s = 0.f;
  for (int i = threadIdx.x * 8; i < HW; i += 2048) {
    uint4 r = *(const uint4*)(plane + i);
    float f[8];
    unpack2(r.x, f[0], f[1]); unpack2(r.y, f[2], f[3]);
    unpack2(r.z, f[4], f[5]); unpack2(r.w, f[6], f[7]);
    #pragma unroll
    for (int j = 0; j < 8; j++) s += f[j] * f[j];
  }
  #pragma unroll
  for (int off = 32; off >= 1; off >>= 1) s += __shfl_down(s, off);
  __shared__ float red[4];
  if ((threadIdx.x & 63) == 0) red[threadIdx.x >> 6] = s;
  __syncthreads();
  if (threadIdx.x == 0)
    inv[id] = 1.f / fmaxf(sqrtf(red[0] + red[1] + red[2] + red[3]), 1e-12f);
}

// ---- attention partials: 16x16 per (b,h), 64 L-chunks of 1024
__global__ __launch_bounds__(256) void attn_partial_kernel(const u16* __restrict__ q,
                                                           const u16* __restrict__ k,
                                                           float* __restrict__ part) {
  int bh = blockIdx.x, chunk = blockIdx.y;
  int b = bh / 6, h = bh % 6;
  int t = threadIdx.x, c = t >> 4, d = t & 15;
  const u16* qp = q + (size_t)(h * 16 + c) * NPIX + (size_t)b * HW + chunk * 1024;
  const u16* kp = k + (size_t)(h * 16 + d) * NPIX + (size_t)b * HW + chunk * 1024;
  float acc = 0.f;
  for (int l = 0; l < 1024; l += 8) {
    uint4 rq = *(const uint4*)(qp + l);
    uint4 rk = *(const uint4*)(kp + l);
    float qa[8], ka[8];
    unpack2(rq.x, qa[0], qa[1]); unpack2(rq.y, qa[2], qa[3]);
    unpack2(rq.z, qa[4], qa[5]); unpack2(rq.w, qa[6], qa[7]);
    unpack2(rk.x, ka[0], ka[1]); unpack2(rk.y, ka[2], ka[3]);
    unpack2(rk.z, ka[4], ka[5]); unpack2(rk.w, ka[6], ka[7]);
    #pragma unroll
    for (int j = 0; j < 8; j++) acc += qa[j] * ka[j];
  }
  part[chunk * 3072 + bh * 256 + t] = acc;
}

// ---- combine partials, scale by norms & temperature, softmax over d
__global__ __launch_bounds__(256) void attn_softmax_kernel(const float* __restrict__ part,
                                                           const float* __restrict__ inv,
                                                           const float* __restrict__ temp,
                                                           float* __restrict__ attn) {
  int bh = blockIdx.x;
  int b = bh / 6, h = bh % 6;
  int t = threadIdx.x;
  int c = t >> 4, d = t & 15;
  float s = 0.f;
  for (int ch = 0; ch < 64; ch++) s += part[ch * 3072 + bh * 256 + t];
  float val = s * inv[b * 96 + h * 16 + c] * inv[192 + b * 96 + h * 16 + d] * temp[h];
  float m = val;
  #pragma unroll
  for (int off = 1; off < 16; off <<= 1) m = fmaxf(m, __shfl_xor(m, off));
  float e = expf(val - m);
  float sum = e;
  #pragma unroll
  for (int off = 1; off < 16; off <<= 1) sum += __shfl_xor(sum, off);
  attn[bh * 256 + t] = e / sum;
}

// ---- out[h*16+c] = sum_d attn[b,h,c,d] * v[h*16+d] per pixel
__global__ __launch_bounds__(256) void attnout_kernel(const float* __restrict__ attn,
                                                      const u16* __restrict__ v,
                                                      u16* __restrict__ out) {
  __shared__ float sA[1536];
  int t = threadIdx.x;
  int p = blockIdx.x * 256 + t;
  int b = p >> 16;
  for (int i = t; i < 1536; i += 256) sA[i] = attn[b * 1536 + i];
  __syncthreads();
  const u16* vb = v + p;
  u16* ob = out + p;
  for (int h = 0; h < 6; h++) {
    float vv[16];
    #pragma unroll
    for (int d = 0; d < 16; d++) vv[d] = b2f(vb[(size_t)(h * 16 + d) * NPIX]);
    #pragma unroll
    for (int c = 0; c < 16; c++) {
      float s = 0.f;
      #pragma unroll
      for (int d = 0; d < 16; d++) s += sA[h * 256 + c * 16 + d] * vv[d];
      ob[(size_t)(h * 16 + c) * NPIX] = f2b(s);
    }
  }
}

extern "C" void kernel_launch(void* const* d_in, const int* in_sizes, int n_in,
                              void* d_out, int out_size, void* d_ws, size_t ws_size,
                              hipStream_t stream) {
  const float* x       = (const float*)d_in[0];
  const float* f1      = (const float*)d_in[1];
  const float* f2      = (const float*)d_in[2];
  const float* qkv_w   = (const float*)d_in[3];
  const float* qkv_dw  = (const float*)d_in[4];
  const float* temp    = (const float*)d_in[5];
  const float* k_dw    = (const float*)d_in[6];
  const float* k_pw    = (const float*)d_in[7];
  const float* v_dw    = (const float*)d_in[8];
  const float* v_pw    = (const float*)d_in[9];
  const float* proj_w  = (const float*)d_in[10];
  const float* ffn_dw1 = (const float*)d_in[11];
  const float* ffn_pm  = (const float*)d_in[12];
  const float* ffn_dw2 = (const float*)d_in[13];
  const float* ffn_po  = (const float*)d_in[14];
  float* out = (float*)d_out;

  u16* wsb = (u16*)d_ws;
  const size_t SLOT = (size_t)96 * NPIX;
  u16* S0 = wsb;
  u16* S1 = wsb + 1 * SLOT;
  u16* S2 = wsb + 2 * SLOT;
  u16* S3 = wsb + 3 * SLOT;
  u16* S4 = wsb + 4 * SLOT;
  float* fscr = (float*)(wsb + 7 * SLOT);
  float* INV  = fscr;                 // 384
  float* PART = fscr + 384;           // 64*3072
  float* ATTN = fscr + 384 + 196608;  // 3072
  u16* WB = (u16*)(fscr + 200064);
  u16* Wqkv = WB;                 // 288*96
  u16* Wkpw = WB + 27648;         // 96*192
  u16* Wvpw = WB + 46080;         // 96*192
  u16* Wproj = WB + 64512;        // 96*96
  u16* Wpm  = WB + 73728;         // 288*288
  u16* Wpo  = WB + 156672;        // 96*288  (total 184320)

  dim3 blk(256);

  wpack_kernel<<<720, blk, 0, stream>>>(qkv_w, 27648, k_pw, 18432, v_pw, 18432,
                                        proj_w, 9216, ffn_pm, 82944, ffn_po, 27648, WB);

  // ---- attention branch ----
  ln_kernel<<<512, blk, 0, stream>>>(x, S0);
  pwm_kernel<96, 288, 0, 0><<<dim3(3, 1024), blk, 0, stream>>>(S0, Wqkv, nullptr, S1);
  // qkv depthwise with slot rotation: q->S0, k->S1, v->S2
  dw3x3_kernel<0><<<dim3(32, 96, 2), blk, 0, stream>>>(S1, 0,   x, 288, 1, qkv_dw,           S0);
  dw3x3_kernel<0><<<dim3(32, 96, 2), blk, 0, stream>>>(S1, 96,  x, 288, 1, qkv_dw + 96 * 9,  S1);
  dw3x3_kernel<0><<<dim3(32, 96, 2), blk, 0, stream>>>(S1, 192, x, 288, 1, qkv_dw + 192 * 9, S2);
  // k path: concat(k=S1, f1) -> dw+gelu -> S3,S4 ; pw -> S1
  dw3x3_kernel<1><<<dim3(32, 192, 2), blk, 0, stream>>>(S1, 0, f1, 96, 1, k_dw, S3);
  pwm_kernel<192, 96, 0, 0><<<dim3(1, 1024), blk, 0, stream>>>(S3, Wkpw, nullptr, S1);
  // v path: concat(v=S2, f2) -> dw+gelu -> S3,S4 ; pw -> S2
  dw3x3_kernel<1><<<dim3(32, 192, 2), blk, 0, stream>>>(S2, 0, f2, 96, 1, v_dw, S3);
  pwm_kernel<192, 96, 0, 0><<<dim3(1, 1024), blk, 0, stream>>>(S3, Wvpw, nullptr, S2);
  // norms + attention matrix + softmax + apply
  l2norm_kernel<<<384, blk, 0, stream>>>(S0, S1, INV);
  attn_partial_kernel<<<dim3(12, 64), blk, 0, stream>>>(S0, S1, PART);
  attn_softmax_kernel<<<12, blk, 0, stream>>>(PART, INV, temp, ATTN);
  attnout_kernel<<<512, blk, 0, stream>>>(ATTN, S2, S3);
  // proj + residual -> d_out (f32, b-major)
  pwm_kernel<96, 96, 0, 1><<<dim3(1, 1024), blk, 0, stream>>>(S3, Wproj, x, out);

  // ---- FFN branch ----
  ln_kernel<<<512, blk, 0, stream>>>(out, S0);
  dw3x3_kernel<0><<<dim3(32, 288, 2), blk, 0, stream>>>(S0, 0, x, 96, 3, ffn_dw1, S1);
  pwm_kernel<288, 288, 1, 0><<<dim3(3, 1024), blk, 0, stream>>>(S1, Wpm, nullptr, S4);
  dw3x3_kernel<0><<<dim3(32, 288, 2), blk, 0, stream>>>(S4, 0, x, 288, 1, ffn_dw2, S1);
  pwm_kernel<288, 96, 0, 1><<<dim3(1, 1024), blk, 0, stream>>>(S1, Wpo, out, out);
}